// Round 6
// baseline (630.402 us; speedup 1.0000x reference)
//
#include <hip/hip_runtime.h>
#include <hip/hip_bf16.h>

#define PED   512
#define HDIM  64
#define EDIM  32
#define NPAIR (PED * PED)          // 262144 rows
#define GATES 256                  // 4*H
#define WF_ELEMS (48 * 64 * 8)     // W frags: [slot][lane][j], slot=(gate_tile*3+ks)
#define NTG   (NPAIR / 128)        // 2048 tile-groups (8 tiles of 16 rows each)
#define GRID  768                  // 3 blocks/CU x 256 CU: LDS-bound residency

typedef __attribute__((ext_vector_type(8))) __bf16 bf16x8;
typedef __attribute__((ext_vector_type(4))) float  floatx4;

__device__ __forceinline__ float sigmoidf_fast(float x) {
    return __builtin_amdgcn_rcpf(1.0f + __expf(-x));
}
__device__ __forceinline__ float tanhf_fast(float x) {
    return fmaf(2.0f, __builtin_amdgcn_rcpf(1.0f + __expf(-2.0f * x)), -1.0f);
}

// ---- prep: weights -> bf16 MFMA A-fragments, LANE-CONTIGUOUS slot layout ----
// Wf[((gate_tile*3 + ks)*64 + lane)*8 + j] = W[gate_tile*16 + (lane&15)]
//                                             [ks*32 + (lane>>4)*8 + j]
__global__ void sra_prep(const float* __restrict__ W_ih, const float* __restrict__ W_hh,
                         const float* __restrict__ b_ih, const float* __restrict__ b_hh,
                         __bf16* __restrict__ Wf, float* __restrict__ bsum)
{
    int tid = blockIdx.x * 256 + threadIdx.x;
    if (tid < WF_ELEMS) {
        int j    = tid & 7;
        int lane = (tid >> 3) & 63;
        int s    = tid >> 9;                    // slot 0..47
        int nt   = s / 3;                       // gate tile 0..15
        int ks   = s - nt * 3;                  // k-step 0..2
        int n = nt * 16 + (lane & 15);          // gate index
        int k = ks * 32 + (lane >> 4) * 8 + j;  // k index
        float w = (k < EDIM) ? W_ih[n * EDIM + k] : W_hh[n * HDIM + (k - EDIM)];
        Wf[tid] = (__bf16)w;
    }
    if (tid < GATES) bsum[tid] = b_ih[tid] + b_hh[tid];
}

// ---- main: persistent blocks. Stage 48KB weight table to LDS ONCE, then
// grid-stride over tile-groups with NO barrier in the loop (shw read-only).
// Steady-state waves are pure load/ds_read/MFMA/store streams -> CU stays
// populated with streaming waves instead of stage/barrier/drain ramps.
__global__ __launch_bounds__(512, 6)
void sra_main(const float* __restrict__ corr,
              const float* __restrict__ ht,
              const float* __restrict__ ct,
              const int*   __restrict__ nei,
              const float* __restrict__ W_emb,
              const float* __restrict__ b_emb,
              const __bf16* __restrict__ Wf,
              const float* __restrict__ bsumg,
              float* __restrict__ h_out,
              float* __restrict__ c_out)
{
    __shared__ __align__(16) __bf16 shw[WF_ELEMS];   // 48 KB
    __shared__ float shb[GATES];                     // 1 KB

    const int tid  = threadIdx.x;
    const int wave = tid >> 6;
    const int lane = tid & 63;
    const int lo   = lane & 15;
    const int qu   = lane >> 4;

    // ---- stage weight table (L2-hot) into LDS once: 3072 x 16B, contiguous
    {
        const floatx4* src = (const floatx4*)Wf;
        floatx4*       dst = (floatx4*)shw;
#pragma unroll
        for (int it = 0; it < 6; ++it)
            dst[it * 512 + tid] = src[it * 512 + tid];
        if (tid < GATES) shb[tid] = bsumg[tid];
    }
    __syncthreads();

    const bf16x8* wp = (const bf16x8*)shw;           // [slot][lane] 16B frags

    for (int tg = blockIdx.x; tg < NTG; tg += GRID) {
        const int row = (tg * 8 + wave) * 16 + lo;   // this lane's pair-row
        const size_t rowoff = (size_t)row * HDIM;

        // ---- per-row global loads ----
        const float2 xy = *(const float2*)(corr + (size_t)row * 2);
        const floatx4 h0a = *(const floatx4*)(ht + rowoff + qu * 8);
        const floatx4 h0b = *(const floatx4*)(ht + rowoff + qu * 8 + 4);
        const floatx4 h1a = *(const floatx4*)(ht + rowoff + 32 + qu * 8);
        const floatx4 h1b = *(const floatx4*)(ht + rowoff + 32 + qu * 8 + 4);
        const bool msk = nei[row] > 0;               // lane-uniform mask

        // ---- x B-frag (k 0..31): embedding + ReLU, in-register ----
        bf16x8 b0;
#pragma unroll
        for (int j = 0; j < 8; ++j) {
            const int e = qu * 8 + j;
            float v = fmaf(xy.x, W_emb[e * 2 + 0], fmaf(xy.y, W_emb[e * 2 + 1], b_emb[e]));
            b0[j] = (__bf16)fmaxf(v, 0.0f);
        }
        // ---- h B-frags (k 32..95) ----
        bf16x8 b1, b2;
#pragma unroll
        for (int j = 0; j < 4; ++j) {
            b1[j]     = (__bf16)h0a[j];
            b1[j + 4] = (__bf16)h0b[j];
            b2[j]     = (__bf16)h1a[j];
            b2[j + 4] = (__bf16)h1b[j];
        }

        // ---- 4 gate-quad groups: 12 ds_read_b128 + 12 MFMA + float4 epilogue
#pragma unroll
        for (int g = 0; g < 4; ++g) {
            const int kb = g * 16 + qu * 4;          // gate sub-index [0,64)

            const floatx4 cold = *(const floatx4*)(ct + rowoff + kb);
            const floatx4 hold = *(const floatx4*)(ht + rowoff + kb);   // L1-hot
            const floatx4 bi4  = *(const floatx4*)(shb + kb);
            const floatx4 bf4  = *(const floatx4*)(shb + 64 + kb);
            const floatx4 bg4  = *(const floatx4*)(shb + 128 + kb);
            const floatx4 bo4  = *(const floatx4*)(shb + 192 + kb);

            const bf16x8 wi0 = wp[((g     ) * 3 + 0) * 64 + lane];
            const bf16x8 wi1 = wp[((g     ) * 3 + 1) * 64 + lane];
            const bf16x8 wi2 = wp[((g     ) * 3 + 2) * 64 + lane];
            const bf16x8 wf0 = wp[((g +  4) * 3 + 0) * 64 + lane];
            const bf16x8 wf1 = wp[((g +  4) * 3 + 1) * 64 + lane];
            const bf16x8 wf2 = wp[((g +  4) * 3 + 2) * 64 + lane];
            const bf16x8 wg0 = wp[((g +  8) * 3 + 0) * 64 + lane];
            const bf16x8 wg1 = wp[((g +  8) * 3 + 1) * 64 + lane];
            const bf16x8 wg2 = wp[((g +  8) * 3 + 2) * 64 + lane];
            const bf16x8 wo0 = wp[((g + 12) * 3 + 0) * 64 + lane];
            const bf16x8 wo1 = wp[((g + 12) * 3 + 1) * 64 + lane];
            const bf16x8 wo2 = wp[((g + 12) * 3 + 2) * 64 + lane];

            const floatx4 z = {0.f, 0.f, 0.f, 0.f};
            floatx4 ai = __builtin_amdgcn_mfma_f32_16x16x32_bf16(wi0, b0, z, 0, 0, 0);
            floatx4 af = __builtin_amdgcn_mfma_f32_16x16x32_bf16(wf0, b0, z, 0, 0, 0);
            floatx4 ag = __builtin_amdgcn_mfma_f32_16x16x32_bf16(wg0, b0, z, 0, 0, 0);
            floatx4 ao = __builtin_amdgcn_mfma_f32_16x16x32_bf16(wo0, b0, z, 0, 0, 0);
            ai = __builtin_amdgcn_mfma_f32_16x16x32_bf16(wi1, b1, ai, 0, 0, 0);
            af = __builtin_amdgcn_mfma_f32_16x16x32_bf16(wf1, b1, af, 0, 0, 0);
            ag = __builtin_amdgcn_mfma_f32_16x16x32_bf16(wg1, b1, ag, 0, 0, 0);
            ao = __builtin_amdgcn_mfma_f32_16x16x32_bf16(wo1, b1, ao, 0, 0, 0);
            ai = __builtin_amdgcn_mfma_f32_16x16x32_bf16(wi2, b2, ai, 0, 0, 0);
            af = __builtin_amdgcn_mfma_f32_16x16x32_bf16(wf2, b2, af, 0, 0, 0);
            ag = __builtin_amdgcn_mfma_f32_16x16x32_bf16(wg2, b2, ag, 0, 0, 0);
            ao = __builtin_amdgcn_mfma_f32_16x16x32_bf16(wo2, b2, ao, 0, 0, 0);

            floatx4 cn4, hn4;
#pragma unroll
            for (int r = 0; r < 4; ++r) {
                const float iv = sigmoidf_fast(ai[r] + bi4[r]);
                const float fv = sigmoidf_fast(af[r] + bf4[r]);
                const float gv = tanhf_fast(ag[r] + bg4[r]);
                const float ov = sigmoidf_fast(ao[r] + bo4[r]);
                const float cn = fv * cold[r] + iv * gv;
                const float hn = ov * tanhf_fast(cn);
                cn4[r] = msk ? cn : cold[r];
                hn4[r] = msk ? hn : hold[r];
            }
            *(floatx4*)(c_out + rowoff + kb) = cn4;
            *(floatx4*)(h_out + rowoff + kb) = hn4;
        }
    }
}

extern "C" void kernel_launch(void* const* d_in, const int* in_sizes, int n_in,
                              void* d_out, int out_size, void* d_ws, size_t ws_size,
                              hipStream_t stream) {
    const float* corr  = (const float*)d_in[0];
    const float* ht    = (const float*)d_in[1];
    const float* ct    = (const float*)d_in[2];
    const int*   nei   = (const int*)  d_in[3];
    const float* W_emb = (const float*)d_in[4];
    const float* b_emb = (const float*)d_in[5];
    const float* W_ih  = (const float*)d_in[6];
    const float* W_hh  = (const float*)d_in[7];
    const float* b_ih  = (const float*)d_in[8];
    const float* b_hh  = (const float*)d_in[9];

    __bf16* Wf   = (__bf16*)d_ws;                        // 49152 B
    float*  bsum = (float*)((char*)d_ws + WF_ELEMS * 2); // 1024 B

    float* hout = (float*)d_out;
    float* cout = hout + (size_t)NPAIR * HDIM;

    hipLaunchKernelGGL(sra_prep, dim3(96), dim3(256), 0, stream,
                       W_ih, W_hh, b_ih, b_hh, Wf, bsum);
    hipLaunchKernelGGL(sra_main, dim3(GRID), dim3(512), 0, stream,
                       corr, ht, ct, nei, W_emb, b_emb, Wf, bsum, hout, cout);
}

// Round 7
// 502.026 us; speedup vs baseline: 1.2557x; 1.2557x over previous
//
#include <hip/hip_runtime.h>
#include <hip/hip_bf16.h>

#define PED   512
#define HDIM  64
#define EDIM  32
#define NPAIR (PED * PED)          // 262144 rows
#define GATES 256                  // 4*H
#define WF_ELEMS (48 * 64 * 8)     // W frags: [slot][lane][j], slot=(gate_tile*3+ks)

typedef __attribute__((ext_vector_type(8))) __bf16 bf16x8;
typedef __attribute__((ext_vector_type(4))) float  floatx4;

__device__ __forceinline__ float sigmoidf_fast(float x) {
    return __builtin_amdgcn_rcpf(1.0f + __expf(-x));
}
__device__ __forceinline__ float tanhf_fast(float x) {
    return fmaf(2.0f, __builtin_amdgcn_rcpf(1.0f + __expf(-2.0f * x)), -1.0f);
}

// ---- prep: weights -> bf16 MFMA A-fragments, LANE-CONTIGUOUS slot layout ----
// Wf[((gate_tile*3 + ks)*64 + lane)*8 + j] = W[gate_tile*16 + (lane&15)]
//                                             [ks*32 + (lane>>4)*8 + j]
__global__ void sra_prep(const float* __restrict__ W_ih, const float* __restrict__ W_hh,
                         const float* __restrict__ b_ih, const float* __restrict__ b_hh,
                         __bf16* __restrict__ Wf, float* __restrict__ bsum)
{
    int tid = blockIdx.x * 256 + threadIdx.x;
    if (tid < WF_ELEMS) {
        int j    = tid & 7;
        int lane = (tid >> 3) & 63;
        int s    = tid >> 9;                    // slot 0..47
        int nt   = s / 3;                       // gate tile 0..15
        int ks   = s - nt * 3;                  // k-step 0..2
        int n = nt * 16 + (lane & 15);          // gate index
        int k = ks * 32 + (lane >> 4) * 8 + j;  // k index
        float w = (k < EDIM) ? W_ih[n * EDIM + k] : W_hh[n * HDIM + (k - EDIM)];
        Wf[tid] = (__bf16)w;
    }
    if (tid < GATES) bsum[tid] = b_ih[tid] + b_hh[tid];
}

// ---- one 16-row tile: 4 gate-quad groups of {ct/ht float4 loads, 12
// ds_read_b128, 12 MFMA, VALU epilogue, 2 float4 stores}. acc layout
// (gate = qu*4+r, row = lo): natural row-major epilogue, no transposes.
__device__ __forceinline__ void do_tile(
    const size_t rowoff, const bool msk,
    const bf16x8 b0, const bf16x8 b1, const bf16x8 b2,
    const bf16x8* __restrict__ wp, const float* __restrict__ shb,
    const int lane, const int qu,
    const float* __restrict__ ht, const float* __restrict__ ct,
    float* __restrict__ h_out, float* __restrict__ c_out)
{
#pragma unroll
    for (int g = 0; g < 4; ++g) {
        const int kb = g * 16 + qu * 4;          // gate sub-index [0,64)

        const floatx4 cold = *(const floatx4*)(ct + rowoff + kb);
        const floatx4 hold = *(const floatx4*)(ht + rowoff + kb);   // L1-hot
        const floatx4 bi4  = *(const floatx4*)(shb + kb);
        const floatx4 bf4  = *(const floatx4*)(shb + 64 + kb);
        const floatx4 bg4  = *(const floatx4*)(shb + 128 + kb);
        const floatx4 bo4  = *(const floatx4*)(shb + 192 + kb);

        const bf16x8 wi0 = wp[((g     ) * 3 + 0) * 64 + lane];
        const bf16x8 wi1 = wp[((g     ) * 3 + 1) * 64 + lane];
        const bf16x8 wi2 = wp[((g     ) * 3 + 2) * 64 + lane];
        const bf16x8 wf0 = wp[((g +  4) * 3 + 0) * 64 + lane];
        const bf16x8 wf1 = wp[((g +  4) * 3 + 1) * 64 + lane];
        const bf16x8 wf2 = wp[((g +  4) * 3 + 2) * 64 + lane];
        const bf16x8 wg0 = wp[((g +  8) * 3 + 0) * 64 + lane];
        const bf16x8 wg1 = wp[((g +  8) * 3 + 1) * 64 + lane];
        const bf16x8 wg2 = wp[((g +  8) * 3 + 2) * 64 + lane];
        const bf16x8 wo0 = wp[((g + 12) * 3 + 0) * 64 + lane];
        const bf16x8 wo1 = wp[((g + 12) * 3 + 1) * 64 + lane];
        const bf16x8 wo2 = wp[((g + 12) * 3 + 2) * 64 + lane];

        const floatx4 z = {0.f, 0.f, 0.f, 0.f};
        floatx4 ai = __builtin_amdgcn_mfma_f32_16x16x32_bf16(wi0, b0, z, 0, 0, 0);
        floatx4 af = __builtin_amdgcn_mfma_f32_16x16x32_bf16(wf0, b0, z, 0, 0, 0);
        floatx4 ag = __builtin_amdgcn_mfma_f32_16x16x32_bf16(wg0, b0, z, 0, 0, 0);
        floatx4 ao = __builtin_amdgcn_mfma_f32_16x16x32_bf16(wo0, b0, z, 0, 0, 0);
        ai = __builtin_amdgcn_mfma_f32_16x16x32_bf16(wi1, b1, ai, 0, 0, 0);
        af = __builtin_amdgcn_mfma_f32_16x16x32_bf16(wf1, b1, af, 0, 0, 0);
        ag = __builtin_amdgcn_mfma_f32_16x16x32_bf16(wg1, b1, ag, 0, 0, 0);
        ao = __builtin_amdgcn_mfma_f32_16x16x32_bf16(wo1, b1, ao, 0, 0, 0);
        ai = __builtin_amdgcn_mfma_f32_16x16x32_bf16(wi2, b2, ai, 0, 0, 0);
        af = __builtin_amdgcn_mfma_f32_16x16x32_bf16(wf2, b2, af, 0, 0, 0);
        ag = __builtin_amdgcn_mfma_f32_16x16x32_bf16(wg2, b2, ag, 0, 0, 0);
        ao = __builtin_amdgcn_mfma_f32_16x16x32_bf16(wo2, b2, ao, 0, 0, 0);

        floatx4 cn4, hn4;
#pragma unroll
        for (int r = 0; r < 4; ++r) {
            const float iv = sigmoidf_fast(ai[r] + bi4[r]);
            const float fv = sigmoidf_fast(af[r] + bf4[r]);
            const float gv = tanhf_fast(ag[r] + bg4[r]);
            const float ov = sigmoidf_fast(ao[r] + bo4[r]);
            const float cn = fv * cold[r] + iv * gv;
            const float hn = ov * tanhf_fast(cn);
            cn4[r] = msk ? cn : cold[r];
            hn4[r] = msk ? hn : hold[r];
        }
        *(floatx4*)(c_out + rowoff + kb) = cn4;
        *(floatx4*)(h_out + rowoff + kb) = hn4;
    }
}

// ---- main: R5 structure (stage 48KB once, one barrier, 1-shot blocks for
// locality — R6 proved unsynced persistence thrashes L2/L3), but each wave
// now computes TWO independent tiles with both tiles' front loads hoisted:
// 2x memory in flight while the other tile occupies VALU/MFMA pipes.
// Block b owns the contiguous 16-tile chunk [b*16, b*16+16): rows adjacent.
__global__ __launch_bounds__(512, 6)
void sra_main(const float* __restrict__ corr,
              const float* __restrict__ ht,
              const float* __restrict__ ct,
              const int*   __restrict__ nei,
              const float* __restrict__ W_emb,
              const float* __restrict__ b_emb,
              const __bf16* __restrict__ Wf,
              const float* __restrict__ bsumg,
              float* __restrict__ h_out,
              float* __restrict__ c_out)
{
    __shared__ __align__(16) __bf16 shw[WF_ELEMS];   // 48 KB
    __shared__ float shb[GATES];                     // 1 KB

    const int tid  = threadIdx.x;
    const int wave = tid >> 6;
    const int lane = tid & 63;
    const int lo   = lane & 15;
    const int qu   = lane >> 4;

    // ---- stage weight table (L2-hot) into LDS once: 3072 x 16B, contiguous
    {
        const floatx4* src = (const floatx4*)Wf;
        floatx4*       dst = (floatx4*)shw;
#pragma unroll
        for (int it = 0; it < 6; ++it)
            dst[it * 512 + tid] = src[it * 512 + tid];
        if (tid < GATES) shb[tid] = bsumg[tid];
    }

    const int tile0 = blockIdx.x * 16 + wave;
    const int tile1 = tile0 + 8;
    const int row0  = tile0 * 16 + lo;
    const int row1  = tile1 * 16 + lo;
    const size_t ro0 = (size_t)row0 * HDIM;
    const size_t ro1 = (size_t)row1 * HDIM;

    // ---- front loads for BOTH tiles issued before any compute ----
    const float2  xy0 = *(const float2*)(corr + (size_t)row0 * 2);
    const float2  xy1 = *(const float2*)(corr + (size_t)row1 * 2);
    const floatx4 h0a0 = *(const floatx4*)(ht + ro0 + qu * 8);
    const floatx4 h0b0 = *(const floatx4*)(ht + ro0 + qu * 8 + 4);
    const floatx4 h1a0 = *(const floatx4*)(ht + ro0 + 32 + qu * 8);
    const floatx4 h1b0 = *(const floatx4*)(ht + ro0 + 32 + qu * 8 + 4);
    const floatx4 h0a1 = *(const floatx4*)(ht + ro1 + qu * 8);
    const floatx4 h0b1 = *(const floatx4*)(ht + ro1 + qu * 8 + 4);
    const floatx4 h1a1 = *(const floatx4*)(ht + ro1 + 32 + qu * 8);
    const floatx4 h1b1 = *(const floatx4*)(ht + ro1 + 32 + qu * 8 + 4);
    const bool msk0 = nei[row0] > 0;
    const bool msk1 = nei[row1] > 0;

    // ---- x B-frags (k 0..31): embedding + ReLU, in-register ----
    bf16x8 b0_0, b0_1;
#pragma unroll
    for (int j = 0; j < 8; ++j) {
        const int e = qu * 8 + j;
        const float we0 = W_emb[e * 2 + 0], we1 = W_emb[e * 2 + 1], be = b_emb[e];
        float v0 = fmaf(xy0.x, we0, fmaf(xy0.y, we1, be));
        float v1 = fmaf(xy1.x, we0, fmaf(xy1.y, we1, be));
        b0_0[j] = (__bf16)fmaxf(v0, 0.0f);
        b0_1[j] = (__bf16)fmaxf(v1, 0.0f);
    }
    // ---- h B-frags (k 32..95) ----
    bf16x8 b1_0, b2_0, b1_1, b2_1;
#pragma unroll
    for (int j = 0; j < 4; ++j) {
        b1_0[j]     = (__bf16)h0a0[j];  b1_0[j + 4] = (__bf16)h0b0[j];
        b2_0[j]     = (__bf16)h1a0[j];  b2_0[j + 4] = (__bf16)h1b0[j];
        b1_1[j]     = (__bf16)h0a1[j];  b1_1[j + 4] = (__bf16)h0b1[j];
        b2_1[j]     = (__bf16)h1a1[j];  b2_1[j + 4] = (__bf16)h1b1[j];
    }

    __syncthreads();

    const bf16x8* wp = (const bf16x8*)shw;           // [slot][lane] 16B frags

    do_tile(ro0, msk0, b0_0, b1_0, b2_0, wp, shb, lane, qu, ht, ct, h_out, c_out);
    do_tile(ro1, msk1, b0_1, b1_1, b2_1, wp, shb, lane, qu, ht, ct, h_out, c_out);
}

extern "C" void kernel_launch(void* const* d_in, const int* in_sizes, int n_in,
                              void* d_out, int out_size, void* d_ws, size_t ws_size,
                              hipStream_t stream) {
    const float* corr  = (const float*)d_in[0];
    const float* ht    = (const float*)d_in[1];
    const float* ct    = (const float*)d_in[2];
    const int*   nei   = (const int*)  d_in[3];
    const float* W_emb = (const float*)d_in[4];
    const float* b_emb = (const float*)d_in[5];
    const float* W_ih  = (const float*)d_in[6];
    const float* W_hh  = (const float*)d_in[7];
    const float* b_ih  = (const float*)d_in[8];
    const float* b_hh  = (const float*)d_in[9];

    __bf16* Wf   = (__bf16*)d_ws;                        // 49152 B
    float*  bsum = (float*)((char*)d_ws + WF_ELEMS * 2); // 1024 B

    float* hout = (float*)d_out;
    float* cout = hout + (size_t)NPAIR * HDIM;

    hipLaunchKernelGGL(sra_prep, dim3(96), dim3(256), 0, stream,
                       W_ih, W_hh, b_ih, b_hh, Wf, bsum);
    hipLaunchKernelGGL(sra_main, dim3(NPAIR / 256), dim3(512), 0, stream,
                       corr, ht, ct, nei, W_emb, b_emb, Wf, bsum, hout, cout);
}

// Round 8
// 354.118 us; speedup vs baseline: 1.7802x; 1.4177x over previous
//
#include <hip/hip_runtime.h>
#include <hip/hip_bf16.h>

#define PED   512
#define HDIM  64
#define EDIM  32
#define NPAIR (PED * PED)          // 262144 rows
#define GATES 256                  // 4*H
#define WF_ELEMS (48 * 64 * 8)     // W frags: [slot][lane][j], slot=(gate_tile*3+ks)

typedef __attribute__((ext_vector_type(8))) __bf16 bf16x8;
typedef __attribute__((ext_vector_type(4))) float  floatx4;

__device__ __forceinline__ float sigmoidf_fast(float x) {
    return __builtin_amdgcn_rcpf(1.0f + __expf(-x));
}
__device__ __forceinline__ float tanhf_fast(float x) {
    return fmaf(2.0f, __builtin_amdgcn_rcpf(1.0f + __expf(-2.0f * x)), -1.0f);
}

// ---- prep: weights -> bf16 MFMA A-fragments, LANE-CONTIGUOUS slot layout ----
// Wf[((gate_tile*3 + ks)*64 + lane)*8 + j] = W[gate_tile*16 + (lane&15)]
//                                             [ks*32 + (lane>>4)*8 + j]
__global__ void sra_prep(const float* __restrict__ W_ih, const float* __restrict__ W_hh,
                         const float* __restrict__ b_ih, const float* __restrict__ b_hh,
                         __bf16* __restrict__ Wf, float* __restrict__ bsum)
{
    int tid = blockIdx.x * 256 + threadIdx.x;
    if (tid < WF_ELEMS) {
        int j    = tid & 7;
        int lane = (tid >> 3) & 63;
        int s    = tid >> 9;                    // slot 0..47
        int nt   = s / 3;                       // gate tile 0..15
        int ks   = s - nt * 3;                  // k-step 0..2
        int n = nt * 16 + (lane & 15);          // gate index
        int k = ks * 32 + (lane >> 4) * 8 + j;  // k index
        float w = (k < EDIM) ? W_ih[n * EDIM + k] : W_hh[n * HDIM + (k - EDIM)];
        Wf[tid] = (__bf16)w;
    }
    if (tid < GATES) bsum[tid] = b_ih[tid] + b_hh[tid];
}

// ---- main: R5 per-wave structure EXACTLY (one 16-row tile per wave,
// processed start-to-finish; R6/R7 proved multi-tile waves amplify DRAM
// traffic 3-5x). Occupancy lever: 1024-thread blocks (16 waves) share ONE
// 48KB LDS stage -> 2 blocks/CU = 32 waves/CU (100%) vs R5's 24 (52% meas).
__global__ __launch_bounds__(1024, 8)
void sra_main(const float* __restrict__ corr,
              const float* __restrict__ ht,
              const float* __restrict__ ct,
              const int*   __restrict__ nei,
              const float* __restrict__ W_emb,
              const float* __restrict__ b_emb,
              const __bf16* __restrict__ Wf,
              const float* __restrict__ bsumg,
              float* __restrict__ h_out,
              float* __restrict__ c_out)
{
    __shared__ __align__(16) __bf16 shw[WF_ELEMS];   // 48 KB
    __shared__ float shb[GATES];                     // 1 KB

    const int tid  = threadIdx.x;
    const int wave = tid >> 6;                       // 0..15
    const int lane = tid & 63;
    const int lo   = lane & 15;
    const int qu   = lane >> 4;

    // ---- stage weight table (L2-hot) into LDS once: 3072 x 16B, contiguous
    {
        const floatx4* src = (const floatx4*)Wf;
        floatx4*       dst = (floatx4*)shw;
#pragma unroll
        for (int it = 0; it < 3; ++it)
            dst[it * 1024 + tid] = src[it * 1024 + tid];
        if (tid < GATES) shb[tid] = bsumg[tid];
    }

    const int tile = blockIdx.x * 16 + wave;
    const int row  = tile * 16 + lo;                 // this lane's pair-row
    const size_t rowoff = (size_t)row * HDIM;

    // ---- per-row global loads issued before the barrier (overlap staging)
    const float2 xy = *(const float2*)(corr + (size_t)row * 2);
    const floatx4 h0a = *(const floatx4*)(ht + rowoff + qu * 8);
    const floatx4 h0b = *(const floatx4*)(ht + rowoff + qu * 8 + 4);
    const floatx4 h1a = *(const floatx4*)(ht + rowoff + 32 + qu * 8);
    const floatx4 h1b = *(const floatx4*)(ht + rowoff + 32 + qu * 8 + 4);
    const bool msk = nei[row] > 0;                   // lane-uniform mask

    // ---- x B-frag (k 0..31): embedding + ReLU, in-register ----
    bf16x8 b0;
#pragma unroll
    for (int j = 0; j < 8; ++j) {
        const int e = qu * 8 + j;
        float v = fmaf(xy.x, W_emb[e * 2 + 0], fmaf(xy.y, W_emb[e * 2 + 1], b_emb[e]));
        b0[j] = (__bf16)fmaxf(v, 0.0f);
    }
    // ---- h B-frags (k 32..95) ----
    bf16x8 b1, b2;
#pragma unroll
    for (int j = 0; j < 4; ++j) {
        b1[j]     = (__bf16)h0a[j];
        b1[j + 4] = (__bf16)h0b[j];
        b2[j]     = (__bf16)h1a[j];
        b2[j + 4] = (__bf16)h1b[j];
    }

    __syncthreads();

    const bf16x8* wp = (const bf16x8*)shw;           // [slot][lane] 16B frags

    // ---- 4 gate-quad groups: 12 ds_read_b128 + 12 MFMA + float4 epilogue ----
#pragma unroll
    for (int g = 0; g < 4; ++g) {
        const int kb = g * 16 + qu * 4;              // gate sub-index [0,64)

        const floatx4 cold = *(const floatx4*)(ct + rowoff + kb);
        const floatx4 hold = *(const floatx4*)(ht + rowoff + kb);   // cache-hot
        const floatx4 bi4  = *(const floatx4*)(shb + kb);
        const floatx4 bf4  = *(const floatx4*)(shb + 64 + kb);
        const floatx4 bg4  = *(const floatx4*)(shb + 128 + kb);
        const floatx4 bo4  = *(const floatx4*)(shb + 192 + kb);

        const bf16x8 wi0 = wp[((g     ) * 3 + 0) * 64 + lane];
        const bf16x8 wi1 = wp[((g     ) * 3 + 1) * 64 + lane];
        const bf16x8 wi2 = wp[((g     ) * 3 + 2) * 64 + lane];
        const bf16x8 wf0 = wp[((g +  4) * 3 + 0) * 64 + lane];
        const bf16x8 wf1 = wp[((g +  4) * 3 + 1) * 64 + lane];
        const bf16x8 wf2 = wp[((g +  4) * 3 + 2) * 64 + lane];
        const bf16x8 wg0 = wp[((g +  8) * 3 + 0) * 64 + lane];
        const bf16x8 wg1 = wp[((g +  8) * 3 + 1) * 64 + lane];
        const bf16x8 wg2 = wp[((g +  8) * 3 + 2) * 64 + lane];
        const bf16x8 wo0 = wp[((g + 12) * 3 + 0) * 64 + lane];
        const bf16x8 wo1 = wp[((g + 12) * 3 + 1) * 64 + lane];
        const bf16x8 wo2 = wp[((g + 12) * 3 + 2) * 64 + lane];

        const floatx4 z = {0.f, 0.f, 0.f, 0.f};
        floatx4 ai = __builtin_amdgcn_mfma_f32_16x16x32_bf16(wi0, b0, z, 0, 0, 0);
        floatx4 af = __builtin_amdgcn_mfma_f32_16x16x32_bf16(wf0, b0, z, 0, 0, 0);
        floatx4 ag = __builtin_amdgcn_mfma_f32_16x16x32_bf16(wg0, b0, z, 0, 0, 0);
        floatx4 ao = __builtin_amdgcn_mfma_f32_16x16x32_bf16(wo0, b0, z, 0, 0, 0);
        ai = __builtin_amdgcn_mfma_f32_16x16x32_bf16(wi1, b1, ai, 0, 0, 0);
        af = __builtin_amdgcn_mfma_f32_16x16x32_bf16(wf1, b1, af, 0, 0, 0);
        ag = __builtin_amdgcn_mfma_f32_16x16x32_bf16(wg1, b1, ag, 0, 0, 0);
        ao = __builtin_amdgcn_mfma_f32_16x16x32_bf16(wo1, b1, ao, 0, 0, 0);
        ai = __builtin_amdgcn_mfma_f32_16x16x32_bf16(wi2, b2, ai, 0, 0, 0);
        af = __builtin_amdgcn_mfma_f32_16x16x32_bf16(wf2, b2, af, 0, 0, 0);
        ag = __builtin_amdgcn_mfma_f32_16x16x32_bf16(wg2, b2, ag, 0, 0, 0);
        ao = __builtin_amdgcn_mfma_f32_16x16x32_bf16(wo2, b2, ao, 0, 0, 0);

        floatx4 cn4, hn4;
#pragma unroll
        for (int r = 0; r < 4; ++r) {
            const float iv = sigmoidf_fast(ai[r] + bi4[r]);
            const float fv = sigmoidf_fast(af[r] + bf4[r]);
            const float gv = tanhf_fast(ag[r] + bg4[r]);
            const float ov = sigmoidf_fast(ao[r] + bo4[r]);
            const float cn = fv * cold[r] + iv * gv;
            const float hn = ov * tanhf_fast(cn);
            cn4[r] = msk ? cn : cold[r];
            hn4[r] = msk ? hn : hold[r];
        }
        *(floatx4*)(c_out + rowoff + kb) = cn4;
        *(floatx4*)(h_out + rowoff + kb) = hn4;
    }
}

extern "C" void kernel_launch(void* const* d_in, const int* in_sizes, int n_in,
                              void* d_out, int out_size, void* d_ws, size_t ws_size,
                              hipStream_t stream) {
    const float* corr  = (const float*)d_in[0];
    const float* ht    = (const float*)d_in[1];
    const float* ct    = (const float*)d_in[2];
    const int*   nei   = (const int*)  d_in[3];
    const float* W_emb = (const float*)d_in[4];
    const float* b_emb = (const float*)d_in[5];
    const float* W_ih  = (const float*)d_in[6];
    const float* W_hh  = (const float*)d_in[7];
    const float* b_ih  = (const float*)d_in[8];
    const float* b_hh  = (const float*)d_in[9];

    __bf16* Wf   = (__bf16*)d_ws;                        // 49152 B
    float*  bsum = (float*)((char*)d_ws + WF_ELEMS * 2); // 1024 B

    float* hout = (float*)d_out;
    float* cout = hout + (size_t)NPAIR * HDIM;

    hipLaunchKernelGGL(sra_prep, dim3(96), dim3(256), 0, stream,
                       W_ih, W_hh, b_ih, b_hh, Wf, bsum);
    hipLaunchKernelGGL(sra_main, dim3(NPAIR / 256), dim3(1024), 0, stream,
                       corr, ht, ct, nei, W_emb, b_emb, Wf, bsum, hout, cout);
}

// Round 9
// 268.336 us; speedup vs baseline: 2.3493x; 1.3197x over previous
//
#include <hip/hip_runtime.h>
#include <hip/hip_bf16.h>

#define PED   512
#define HDIM  64
#define EDIM  32
#define NPAIR (PED * PED)          // 262144 rows
#define GATES 256                  // 4*H
#define WF_ELEMS (48 * 64 * 8)     // W frags: [slot][lane][j], slot=(gate_tile*3+ks)

typedef __attribute__((ext_vector_type(8))) __bf16 bf16x8;
typedef __attribute__((ext_vector_type(4))) float  floatx4;

__device__ __forceinline__ float sigmoidf_fast(float x) {
    return __builtin_amdgcn_rcpf(1.0f + __expf(-x));
}
__device__ __forceinline__ float tanhf_fast(float x) {
    return fmaf(2.0f, __builtin_amdgcn_rcpf(1.0f + __expf(-2.0f * x)), -1.0f);
}

// ---- prep: weights -> bf16 MFMA A-fragments, LANE-CONTIGUOUS slot layout ----
// Wf[((gate_tile*3 + ks)*64 + lane)*8 + j] = W[gate_tile*16 + (lane&15)]
//                                             [ks*32 + (lane>>4)*8 + j]
__global__ void sra_prep(const float* __restrict__ W_ih, const float* __restrict__ W_hh,
                         const float* __restrict__ b_ih, const float* __restrict__ b_hh,
                         __bf16* __restrict__ Wf, float* __restrict__ bsum)
{
    int tid = blockIdx.x * 256 + threadIdx.x;
    if (tid < WF_ELEMS) {
        int j    = tid & 7;
        int lane = (tid >> 3) & 63;
        int s    = tid >> 9;                    // slot 0..47
        int nt   = s / 3;                       // gate tile 0..15
        int ks   = s - nt * 3;                  // k-step 0..2
        int n = nt * 16 + (lane & 15);          // gate index
        int k = ks * 32 + (lane >> 4) * 8 + j;  // k index
        float w = (k < EDIM) ? W_ih[n * EDIM + k] : W_hh[n * HDIM + (k - EDIM)];
        Wf[tid] = (__bf16)w;
    }
    if (tid < GATES) bsum[tid] = b_ih[tid] + b_hh[tid];
}

// ---- main: R5 shell EXACTLY (512 thr, 8 waves, one 16-row tile per wave,
// 2048 one-shot blocks, 128-row contiguous span — R6/R7/R8 proved any
// concurrency increase beyond this amplifies DRAM traffic via L2 overflow).
// New: ALL 14 per-row reads (corr, nei, B-frags, cold x4, hold x4) issued
// before the barrier and PINNED in regs via empty asm (anti-remat, R4's
// failure mode). Doubles outstanding HBM reads/wave; per-g loop is pure
// LDS+MFMA+VALU+store.
__global__ __launch_bounds__(512, 6)
void sra_main(const float* __restrict__ corr,
              const float* __restrict__ ht,
              const float* __restrict__ ct,
              const int*   __restrict__ nei,
              const float* __restrict__ W_emb,
              const float* __restrict__ b_emb,
              const __bf16* __restrict__ Wf,
              const float* __restrict__ bsumg,
              float* __restrict__ h_out,
              float* __restrict__ c_out)
{
    __shared__ __align__(16) __bf16 shw[WF_ELEMS];   // 48 KB
    __shared__ float shb[GATES];                     // 1 KB

    const int tid  = threadIdx.x;
    const int wave = tid >> 6;
    const int lane = tid & 63;
    const int lo   = lane & 15;
    const int qu   = lane >> 4;

    const int tile = blockIdx.x * 8 + wave;
    const int row  = tile * 16 + lo;                 // this lane's pair-row
    const size_t rowoff = (size_t)row * HDIM;

    // ---- ALL per-row global reads issued up front (max MLP) ----
    const float2 xy = *(const float2*)(corr + (size_t)row * 2);
    const floatx4 h0a = *(const floatx4*)(ht + rowoff + qu * 8);
    const floatx4 h0b = *(const floatx4*)(ht + rowoff + qu * 8 + 4);
    const floatx4 h1a = *(const floatx4*)(ht + rowoff + 32 + qu * 8);
    const floatx4 h1b = *(const floatx4*)(ht + rowoff + 32 + qu * 8 + 4);
    floatx4 cold0 = *(const floatx4*)(ct + rowoff +      qu * 4);
    floatx4 cold1 = *(const floatx4*)(ct + rowoff + 16 + qu * 4);
    floatx4 cold2 = *(const floatx4*)(ct + rowoff + 32 + qu * 4);
    floatx4 cold3 = *(const floatx4*)(ct + rowoff + 48 + qu * 4);
    floatx4 hold0 = *(const floatx4*)(ht + rowoff +      qu * 4);
    floatx4 hold1 = *(const floatx4*)(ht + rowoff + 16 + qu * 4);
    floatx4 hold2 = *(const floatx4*)(ht + rowoff + 32 + qu * 4);
    floatx4 hold3 = *(const floatx4*)(ht + rowoff + 48 + qu * 4);
    const bool msk = nei[row] > 0;                   // lane-uniform mask

    // ---- stage weight table (L2-hot) into LDS: 3072 x 16B, contiguous ----
    {
        const floatx4* src = (const floatx4*)Wf;
        floatx4*       dst = (floatx4*)shw;
#pragma unroll
        for (int it = 0; it < 6; ++it)
            dst[it * 512 + tid] = src[it * 512 + tid];
        if (tid < GATES) shb[tid] = bsumg[tid];
    }

    // ---- x B-frag (k 0..31): embedding + ReLU, in-register ----
    bf16x8 b0;
#pragma unroll
    for (int j = 0; j < 8; ++j) {
        const int e = qu * 8 + j;
        float v = fmaf(xy.x, W_emb[e * 2 + 0], fmaf(xy.y, W_emb[e * 2 + 1], b_emb[e]));
        b0[j] = (__bf16)fmaxf(v, 0.0f);
    }
    // ---- h B-frags (k 32..95) ----
    bf16x8 b1, b2;
#pragma unroll
    for (int j = 0; j < 4; ++j) {
        b1[j]     = (__bf16)h0a[j];
        b1[j + 4] = (__bf16)h0b[j];
        b2[j]     = (__bf16)h1a[j];
        b2[j + 4] = (__bf16)h1b[j];
    }

    // pin hoisted epilogue operands in VGPRs: forbids rematerialization /
    // sinking of the loads past the barrier (R4's silent failure mode)
    asm volatile("" : "+v"(cold0), "+v"(cold1), "+v"(cold2), "+v"(cold3),
                      "+v"(hold0), "+v"(hold1), "+v"(hold2), "+v"(hold3));

    __syncthreads();   // vmcnt(0) drain: all reads land here, overlapped

    const bf16x8* wp = (const bf16x8*)shw;           // [slot][lane] 16B frags

    const floatx4 colds[4] = {cold0, cold1, cold2, cold3};
    const floatx4 holds[4] = {hold0, hold1, hold2, hold3};

    // ---- 4 gate-quad groups: 12 ds_read_b128 + 12 MFMA + VALU + 2 stores ----
#pragma unroll
    for (int g = 0; g < 4; ++g) {
        const int kb = g * 16 + qu * 4;              // gate sub-index [0,64)

        const floatx4 cold = colds[g];
        const floatx4 hold = holds[g];
        const floatx4 bi4  = *(const floatx4*)(shb + kb);
        const floatx4 bf4  = *(const floatx4*)(shb + 64 + kb);
        const floatx4 bg4  = *(const floatx4*)(shb + 128 + kb);
        const floatx4 bo4  = *(const floatx4*)(shb + 192 + kb);

        const bf16x8 wi0 = wp[((g     ) * 3 + 0) * 64 + lane];
        const bf16x8 wi1 = wp[((g     ) * 3 + 1) * 64 + lane];
        const bf16x8 wi2 = wp[((g     ) * 3 + 2) * 64 + lane];
        const bf16x8 wf0 = wp[((g +  4) * 3 + 0) * 64 + lane];
        const bf16x8 wf1 = wp[((g +  4) * 3 + 1) * 64 + lane];
        const bf16x8 wf2 = wp[((g +  4) * 3 + 2) * 64 + lane];
        const bf16x8 wg0 = wp[((g +  8) * 3 + 0) * 64 + lane];
        const bf16x8 wg1 = wp[((g +  8) * 3 + 1) * 64 + lane];
        const bf16x8 wg2 = wp[((g +  8) * 3 + 2) * 64 + lane];
        const bf16x8 wo0 = wp[((g + 12) * 3 + 0) * 64 + lane];
        const bf16x8 wo1 = wp[((g + 12) * 3 + 1) * 64 + lane];
        const bf16x8 wo2 = wp[((g + 12) * 3 + 2) * 64 + lane];

        const floatx4 z = {0.f, 0.f, 0.f, 0.f};
        floatx4 ai = __builtin_amdgcn_mfma_f32_16x16x32_bf16(wi0, b0, z, 0, 0, 0);
        floatx4 af = __builtin_amdgcn_mfma_f32_16x16x32_bf16(wf0, b0, z, 0, 0, 0);
        floatx4 ag = __builtin_amdgcn_mfma_f32_16x16x32_bf16(wg0, b0, z, 0, 0, 0);
        floatx4 ao = __builtin_amdgcn_mfma_f32_16x16x32_bf16(wo0, b0, z, 0, 0, 0);
        ai = __builtin_amdgcn_mfma_f32_16x16x32_bf16(wi1, b1, ai, 0, 0, 0);
        af = __builtin_amdgcn_mfma_f32_16x16x32_bf16(wf1, b1, af, 0, 0, 0);
        ag = __builtin_amdgcn_mfma_f32_16x16x32_bf16(wg1, b1, ag, 0, 0, 0);
        ao = __builtin_amdgcn_mfma_f32_16x16x32_bf16(wo1, b1, ao, 0, 0, 0);
        ai = __builtin_amdgcn_mfma_f32_16x16x32_bf16(wi2, b2, ai, 0, 0, 0);
        af = __builtin_amdgcn_mfma_f32_16x16x32_bf16(wf2, b2, af, 0, 0, 0);
        ag = __builtin_amdgcn_mfma_f32_16x16x32_bf16(wg2, b2, ag, 0, 0, 0);
        ao = __builtin_amdgcn_mfma_f32_16x16x32_bf16(wo2, b2, ao, 0, 0, 0);

        floatx4 cn4, hn4;
#pragma unroll
        for (int r = 0; r < 4; ++r) {
            const float iv = sigmoidf_fast(ai[r] + bi4[r]);
            const float fv = sigmoidf_fast(af[r] + bf4[r]);
            const float gv = tanhf_fast(ag[r] + bg4[r]);
            const float ov = sigmoidf_fast(ao[r] + bo4[r]);
            const float cn = fv * cold[r] + iv * gv;
            const float hn = ov * tanhf_fast(cn);
            cn4[r] = msk ? cn : cold[r];
            hn4[r] = msk ? hn : hold[r];
        }
        *(floatx4*)(c_out + rowoff + kb) = cn4;
        *(floatx4*)(h_out + rowoff + kb) = hn4;
    }
}

extern "C" void kernel_launch(void* const* d_in, const int* in_sizes, int n_in,
                              void* d_out, int out_size, void* d_ws, size_t ws_size,
                              hipStream_t stream) {
    const float* corr  = (const float*)d_in[0];
    const float* ht    = (const float*)d_in[1];
    const float* ct    = (const float*)d_in[2];
    const int*   nei   = (const int*)  d_in[3];
    const float* W_emb = (const float*)d_in[4];
    const float* b_emb = (const float*)d_in[5];
    const float* W_ih  = (const float*)d_in[6];
    const float* W_hh  = (const float*)d_in[7];
    const float* b_ih  = (const float*)d_in[8];
    const float* b_hh  = (const float*)d_in[9];

    __bf16* Wf   = (__bf16*)d_ws;                        // 49152 B
    float*  bsum = (float*)((char*)d_ws + WF_ELEMS * 2); // 1024 B

    float* hout = (float*)d_out;
    float* cout = hout + (size_t)NPAIR * HDIM;

    hipLaunchKernelGGL(sra_prep, dim3(96), dim3(256), 0, stream,
                       W_ih, W_hh, b_ih, b_hh, Wf, bsum);
    hipLaunchKernelGGL(sra_main, dim3(NPAIR / 128), dim3(512), 0, stream,
                       corr, ht, ct, nei, W_emb, b_emb, Wf, bsum, hout, cout);
}